// Round 8
// baseline (346.381 us; speedup 1.0000x reference)
//
#include <hip/hip_runtime.h>

#define N_NODES 32000
#define NPG     1000
#define BSZ     32
#define NEDGE   512000
#define H       128
#define NL      3
#define NR      8
#define NKK     1152    // B K dim: 8*128 rel chunks + 128 self chunk
#define NKA     1024    // A K dim (rel chunks only; self read from h directly)
#define NBIN2   262144  // 32768 dst bins x 8 rel sub-bins (pow2-padded; bins >= 256000 empty)

typedef __attribute__((ext_vector_type(8))) short short8;
typedef __attribute__((ext_vector_type(4))) float float4v;
typedef __attribute__((ext_vector_type(4))) unsigned int uint4v;

__device__ __forceinline__ float bf2f(unsigned short u) {
  union { unsigned int i; float f; } v;
  v.i = ((unsigned int)u) << 16;
  return v.f;
}
__device__ __forceinline__ unsigned short f2bf(float f) {
  union { float f; unsigned int i; } v;
  v.f = f;
  unsigned int x = v.i;
  return (unsigned short)((x + 0x7FFFu + ((x >> 16) & 1u)) >> 16);  // RNE
}

// direct global->LDS DMA, 16B per lane (dest = wave-uniform base + lane*16)
__device__ __forceinline__ void gl_lds16(const void* g, void* l) {
  __builtin_amdgcn_global_load_lds((__attribute__((address_space(1))) void*)g,
                                   (__attribute__((address_space(3))) void*)l,
                                   16, 0, 0);
}

// ---------------- fused prep: cvtX | cvtB | per-(dst,rel) count | graph hist ----------
__global__ __launch_bounds__(256) void k_prep(
    const float* __restrict__ x, const float* __restrict__ W_rel,
    const float* __restrict__ W_self, const int* __restrict__ dst,
    const int* __restrict__ etype, const int* __restrict__ graph_id,
    unsigned short* __restrict__ hb, unsigned short* __restrict__ Bt,
    int* __restrict__ cnt, int* __restrict__ gcount)
{
  const int b = blockIdx.x, t = threadIdx.x;
  if (b < 4000) {                       // x fp32 -> h0 bf16
    const size_t i = ((size_t)b * 256 + t) * 4;
    float4 v = *(const float4*)(x + i);
    ushort4 u = { f2bf(v.x), f2bf(v.y), f2bf(v.z), f2bf(v.w) };
    *(ushort4*)(hb + i) = u;
  } else if (b < 5728) {                // weights -> Bt2[l][o=0..127][kk=0..1151]
    const int g = (b - 4000) * 256 + t;  // 0..442367 enumerates (l, o, kk)
    const int l = g / (H * NKK);
    const int rem = g - l * (H * NKK);
    const int o = rem / NKK;
    const int kk = rem - o * NKK;
    float v = (kk < 1024)
        ? W_rel[(((size_t)l * NR + (kk >> 7)) * H + (kk & 127)) * H + o]
        : W_self[((size_t)l * H + (kk - 1024)) * H + o];
    Bt[g] = f2bf(v);
  } else if (b < 7728) {                // per-(dst,rel) edge counts
    const int e = (b - 5728) * 256 + t;
    atomicAdd(&cnt[dst[e] * 8 + etype[e]], 1);
  } else {                              // graph histogram (125 blocks)
    __shared__ int hist[BSZ];
    if (t < BSZ) hist[t] = 0;
    __syncthreads();
    const int n = (b - 7728) * 256 + t;
    if (n < N_NODES) atomicAdd(&hist[graph_id[n]], 1);
    __syncthreads();
    if (t < BSZ) { int v = hist[t]; if (v) atomicAdd(&gcount[t], v); }
  }
}

// ---------------- 2-phase exclusive scan over NBIN2 bins ----------
__global__ __launch_bounds__(256) void k_scanA(const int* __restrict__ cnt,
                                               int* __restrict__ bsum) {
  __shared__ int red[256];
  const int t = threadIdx.x;
  int4 v = *(const int4*)(cnt + blockIdx.x * 1024 + t * 4);
  red[t] = v.x + v.y + v.z + v.w;
  __syncthreads();
  for (int off = 128; off > 0; off >>= 1) {
    if (t < off) red[t] += red[t + off];
    __syncthreads();
  }
  if (t == 0) bsum[blockIdx.x] = red[0];
}

__global__ __launch_bounds__(256) void k_scanC(const int* __restrict__ cnt,
                                               const int* __restrict__ bsum,
                                               int* __restrict__ row_ptr2,
                                               int* __restrict__ cursor) {
  __shared__ int ts[256], bsx[256];
  const int t = threadIdx.x;
  const int base = blockIdx.x * 1024 + t * 4;
  int4 v = *(const int4*)(cnt + base);
  const int s = v.x + v.y + v.z + v.w;
  ts[t]  = s;
  bsx[t] = bsum[t];
  __syncthreads();
  for (int off = 1; off < 256; off <<= 1) {   // inclusive Hillis-Steele, both arrays
    int a = (t >= off) ? ts[t - off]  : 0;
    int c = (t >= off) ? bsx[t - off] : 0;
    __syncthreads();
    ts[t] += a; bsx[t] += c;
    __syncthreads();
  }
  const int boff = (blockIdx.x == 0) ? 0 : bsx[blockIdx.x - 1];
  int ex = ts[t] - s + boff;
  int4 w = { ex, ex + v.x, ex + v.x + v.y, ex + v.x + v.y + v.z };
  *(int4*)(row_ptr2 + base) = w;
  *(int4*)(cursor + base) = w;
}

// ---------------- fill: edge_off[p] = src, grouped by (dst,rel) ----
__global__ void k_fill(const int* __restrict__ src, const int* __restrict__ dst,
                       const int* __restrict__ etype, int* __restrict__ cursor,
                       int* __restrict__ edge_off) {
  int e = blockIdx.x * blockDim.x + threadIdx.x;
  if (e < NEDGE) {
    int p = atomicAdd(&cursor[dst[e] * 8 + etype[e]], 1);
    edge_off[p] = src[e];
  }
}

// ---------------- aggregate: A[n][r*128+i] = sum_{e in bin(n,r)} h[src_e][i] ---------
// v5: v4 structure + NONTEMPORAL A stores (A is write-once-read-next-kernel; without
// nt the 65.5MB stream evicts the h rows being gathered ~16x each from L2).
__global__ __launch_bounds__(256) void k_agg(
    const unsigned short* __restrict__ Hin,   // [N,128] bf16
    const int* __restrict__ row_ptr2,         // [N*8+1] bin offsets
    const int* __restrict__ edge_off,         // [E] src node ids
    unsigned short* __restrict__ A)           // [N,1024] bf16
{
  const int tid = threadIdx.x;
  const int j  = tid >> 5;          // rel bin 0..7
  const int li = tid & 31;
  const int p  = li >> 4;           // edge parity
  const int q  = li & 15;           // col chunk: cols q*8 .. q*8+7
  const int n  = blockIdx.x;
  const uint4* H4 = (const uint4*)Hin;   // one h row = 16 uint4
  const int b = row_ptr2[n * 8 + j];
  const int e = row_ptr2[n * 8 + j + 1];
  float acc[8] = {0.f, 0.f, 0.f, 0.f, 0.f, 0.f, 0.f, 0.f};
#define ACC8(u, ok) { \
    const unsigned int xx = (ok) ? (u).x : 0u, yy = (ok) ? (u).y : 0u; \
    const unsigned int zz = (ok) ? (u).z : 0u, ww = (ok) ? (u).w : 0u; \
    acc[0] += bf2f((unsigned short)(xx & 0xffff)); \
    acc[1] += bf2f((unsigned short)(xx >> 16));    \
    acc[2] += bf2f((unsigned short)(yy & 0xffff)); \
    acc[3] += bf2f((unsigned short)(yy >> 16));    \
    acc[4] += bf2f((unsigned short)(zz & 0xffff)); \
    acc[5] += bf2f((unsigned short)(zz >> 16));    \
    acc[6] += bf2f((unsigned short)(ww & 0xffff)); \
    acc[7] += bf2f((unsigned short)(ww >> 16)); }
  for (int k = b + p; k < e; k += 4) {   // this parity's edges: k, k+2
    const int k1 = k + 2;
    const bool v1 = k1 < e;
    const int o0 = edge_off[k];
    const int o1 = edge_off[v1 ? k1 : k];
    uint4 u0 = H4[(size_t)o0 * 16 + q];
    uint4 u1 = H4[(size_t)o1 * 16 + q];
    ACC8(u0, true)
    ACC8(u1, v1)
  }
#undef ACC8
  #pragma unroll
  for (int i = 0; i < 8; ++i) acc[i] += __shfl_xor(acc[i], 16);
  if (p == 0) {
    uint4v w = {
      (unsigned int)f2bf(acc[0]) | ((unsigned int)f2bf(acc[1]) << 16),
      (unsigned int)f2bf(acc[2]) | ((unsigned int)f2bf(acc[3]) << 16),
      (unsigned int)f2bf(acc[4]) | ((unsigned int)f2bf(acc[5]) << 16),
      (unsigned int)f2bf(acc[6]) | ((unsigned int)f2bf(acc[7]) << 16) };
    __builtin_nontemporal_store(w, (uint4v*)(A + (size_t)n * NKA + j * H + q * 8));
  }
}

// ---------------- GEMM: Hout = relu([A | h] @ Bt2^T), K = 1024 + 128 ------------------
// v6: 3-buffer, 2-tiles-ahead counted-vmcnt pipeline. Steady state: 12 loads (2 future
// tiles x 6) in flight across the wait -> latency budget = 2 K-steps + cross-block.
// kt 0..15 stage from A; kt 16,17 self cols from Hin. Fused gmean in epilogue.
__global__ __launch_bounds__(256, 2) void k_gemmA(
    const unsigned short* __restrict__ Ag,    // [32000][1024] bf16
    const unsigned short* __restrict__ Bg,    // [128][1152]   bf16
    const unsigned short* __restrict__ Hin,   // [32000][128]  bf16 (self operand)
    unsigned short* __restrict__ Hout,        // [32000][128]  bf16
    float* __restrict__ gmean, int layer)
{
  __shared__ __align__(16) unsigned short pool[36864];  // 3 bufs x (a[4096] b[8192])
  const int tid = threadIdx.x;
  const int w = tid >> 6, lane = tid & 63;
  const int l15 = lane & 15, quad = lane >> 4;
  const int m0 = blockIdx.x * 64;
  const int rbase = (w & 1) * 32;     // C row group (M): 0 or 32
  const int cbase = (w >> 1) * 64;    // C col group (N): 0 or 64

  float4v acc[2][4];
  #pragma unroll
  for (int i = 0; i < 2; ++i)
    #pragma unroll
    for (int jj = 0; jj < 4; ++jj) acc[i][jj] = (float4v){0.f, 0.f, 0.f, 0.f};

  // stage helpers: 2 + 4 = 6 gl_lds per thread per K-tile
  auto stageA = [&](unsigned short* dstL, const int kb) {
    #pragma unroll
    for (int rep = 0; rep < 2; ++rep) {
      const int g = rep * 256 + tid, row = g >> 3, c = g & 7;
      const unsigned short* srcp = (kb < NKA)
          ? Ag  + (size_t)(m0 + row) * NKA + kb + ((c ^ (row & 7)) * 8)
          : Hin + (size_t)(m0 + row) * H + (kb - NKA) + ((c ^ (row & 7)) * 8);
      gl_lds16(srcp, dstL + (size_t)g * 8);
    }
  };
  auto stageB = [&](unsigned short* dstL, const int kb) {
    #pragma unroll
    for (int rep = 0; rep < 4; ++rep) {
      const int g = rep * 256 + tid, row = g >> 3, c = g & 7;
      gl_lds16(Bg + (size_t)row * NKK + kb + ((c ^ (row & 7)) * 8), dstL + (size_t)g * 8);
    }
  };
  auto compute = [&](const unsigned short* ac, const unsigned short* bc) {
    #pragma unroll
    for (int s = 0; s < 2; ++s) {
      const int c = s * 4 + quad;    // 16B chunk index within 128B row
      short8 af[2], bfv[4];
      #pragma unroll
      for (int i = 0; i < 2; ++i) {
        const int row = rbase + i * 16 + l15;
        af[i] = *(const short8*)(ac + row * 64 + ((c ^ (row & 7)) * 8));
      }
      #pragma unroll
      for (int jj = 0; jj < 4; ++jj) {
        const int orow = cbase + jj * 16 + l15;
        bfv[jj] = *(const short8*)(bc + orow * 64 + ((c ^ (orow & 7)) * 8));
      }
      #pragma unroll
      for (int i = 0; i < 2; ++i)
        #pragma unroll
        for (int jj = 0; jj < 4; ++jj)
          acc[i][jj] = __builtin_amdgcn_mfma_f32_16x16x32_bf16(af[i], bfv[jj], acc[i][jj], 0, 0, 0);
    }
  };

#define STEP(KT, CUR, NXT)                                              \
  {                                                                     \
    if ((KT) + 2 < 18) {                                                \
      stageA(pool + (NXT), ((KT) + 2) * 64);                            \
      stageB(pool + (NXT) + 4096, ((KT) + 2) * 64);                     \
      asm volatile("s_waitcnt vmcnt(12)" ::: "memory");                 \
    } else if ((KT) + 1 < 18) {                                         \
      asm volatile("s_waitcnt vmcnt(6)" ::: "memory");                  \
    } else {                                                            \
      asm volatile("s_waitcnt vmcnt(0)" ::: "memory");                  \
    }                                                                   \
    __builtin_amdgcn_s_barrier();                                       \
    __builtin_amdgcn_sched_barrier(0);                                  \
    compute(pool + (CUR), pool + (CUR) + 4096);                         \
    __builtin_amdgcn_sched_barrier(0);                                  \
    __builtin_amdgcn_s_barrier();                                       \
  }

  // prologue: tiles 0,1 into bufs 0,1 (12 loads in flight)
  stageA(pool, 0);            stageB(pool + 4096, 0);
  stageA(pool + 12288, 64);   stageB(pool + 12288 + 4096, 64);

  for (int kt = 0; kt < 18; kt += 3) {
    STEP(kt,     0,     24576);   // tile kt   in buf0, stage kt+2 -> buf2
    STEP(kt + 1, 12288, 0);       // tile kt+1 in buf1, stage kt+3 -> buf0
    STEP(kt + 2, 24576, 12288);   // tile kt+2 in buf2, stage kt+4 -> buf1
  }
#undef STEP

  // epilogue: relu -> bf16 repack in LDS (stride 136) -> coalesced uint4 stores
  #pragma unroll
  for (int i = 0; i < 2; ++i)
    #pragma unroll
    for (int jj = 0; jj < 4; ++jj)
      #pragma unroll
      for (int r = 0; r < 4; ++r) {
        const int row = rbase + i * 16 + quad * 4 + r;
        const int col = cbase + jj * 16 + l15;
        pool[row * 136 + col] = f2bf(fmaxf(acc[i][jj][r], 0.f));
      }
  __syncthreads();
  #pragma unroll
  for (int rep = 0; rep < 4; ++rep) {
    const int g = rep * 256 + tid;  // 1024 chunks = 64 rows x 16
    const int row = g >> 4, c = g & 15;
    *(uint4*)(Hout + (size_t)(m0 + row) * H + c * 8) = *(const uint4*)(pool + row * 136 + c * 8);
  }

  // fused per-graph mean accumulation (block straddles <= 1 graph boundary)
  const int g0 = m0 / NPG;
  const int bnd = (g0 + 1) * NPG - m0;   // rows of this tile belonging to g0
  if (tid < H) {
    float s0 = 0.f, s1 = 0.f;
    #pragma unroll 8
    for (int r2 = 0; r2 < 64; ++r2) {
      float v = bf2f(pool[r2 * 136 + tid]);
      if (r2 < bnd) s0 += v; else s1 += v;
    }
    atomicAdd(&gmean[(size_t)g0 * (NL * H) + layer * H + tid], s0);
    if (bnd < 64)
      atomicAdd(&gmean[(size_t)(g0 + 1) * (NL * H) + layer * H + tid], s1);
  }
}

// ---------------- readout ----------------
__global__ __launch_bounds__(128) void k_final(
    const unsigned short* __restrict__ hb, const float* __restrict__ gmean,
    const int* __restrict__ gcount,
    const float* __restrict__ rel_tb, const float* __restrict__ Zn,
    const float* __restrict__ projW, const float* __restrict__ projB,
    const float* __restrict__ fcW, const float* __restrict__ fcB,
    const float* __restrict__ repSeq,
    const int* __restrict__ head_ids, const int* __restrict__ tail_ids,
    const int* __restrict__ rel_lab, float* __restrict__ out)
{
  const int b = blockIdx.x;
  const int o = threadIdx.x;   // 128
  __shared__ float gm[384], hf[384], tf[384];
  __shared__ float go[128], ho[128], t_o[128], re[128], rs[128], sv[128];
  __shared__ float lg[128], pr[128], red[128], att[3];

  const int hid = head_ids[b], tlid = tail_ids[b], rl = rel_lab[b];
  const float cinv = 1.f / (float)gcount[b];
  #pragma unroll
  for (int l = 0; l < NL; ++l) {
    gm[l * H + o] = gmean[(size_t)b * (NL * H) + l * H + o] * cinv;
    hf[l * H + o] = bf2f(hb[((size_t)(l + 1) * N_NODES + hid) * H + o]);
    tf[l * H + o] = bf2f(hb[((size_t)(l + 1) * N_NODES + tlid) * H + o]);
  }
  re[o] = rel_tb[rl * H + o];
  rs[o] = repSeq[b * H + o];
  __syncthreads();

  float pb = projB[o];
  float sg = pb, sh = pb, st = pb;
  for (int i = 0; i < NL * H; ++i) {
    float wv = projW[i * H + o];
    sg = fmaf(gm[i], wv, sg);
    sh = fmaf(hf[i], wv, sh);
    st = fmaf(tf[i], wv, st);
  }
  go[o] = (sg > 0.f) ? sg : 0.01f * sg;
  ho[o] = sh;
  t_o[o] = st;
  __syncthreads();

  {
    const int k = o & 63;
    const float* v = (o < 64) ? ho : t_o;
    float s = 0.f;
    for (int i = 0; i < H; ++i) s = fmaf(v[i], Zn[k * H + i], s);
    lg[o] = s;
  }
  __syncthreads();
  if (o < 2) {
    float* l0 = &lg[o * 64];
    float* p0 = &pr[o * 64];
    float mx = l0[0];
    for (int k = 1; k < 64; ++k) mx = fmaxf(mx, l0[k]);
    float sum = 0.f;
    for (int k = 0; k < 64; ++k) { float e = __expf(l0[k] - mx); p0[k] = e; sum += e; }
    float inv = 1.f / sum;
    for (int k = 0; k < 64; ++k) p0[k] *= inv;
  }
  __syncthreads();
  {
    float s1 = 0.f, s2 = 0.f;
    for (int k = 0; k < 64; ++k) {
      float z = Zn[k * H + o];
      s1 = fmaf(pr[k], z, s1);
      s2 = fmaf(pr[64 + k], z, s2);
    }
    s1 = 1.f / (1.f + __expf(-s1));
    s2 = 1.f / (1.f + __expf(-s2));
    sv[o] = s1 * s2;
  }
  __syncthreads();
  if (o == 0) {
    float d0 = 0.f, d1 = 0.f, d2 = 0.f;
    for (int i = 0; i < H; ++i) { d0 += re[i] * go[i]; d1 += re[i] * rs[i]; d2 += re[i] * sv[i]; }
    float mx = fmaxf(d0, fmaxf(d1, d2));
    float e0 = __expf(d0 - mx), e1 = __expf(d1 - mx), e2 = __expf(d2 - mx);
    float inv = 1.f / (e0 + e1 + e2);
    att[0] = e0 * inv; att[1] = e1 * inv; att[2] = e2 * inv;
  }
  __syncthreads();
  float va = att[0] * go[o] + att[1] * rs[o] + att[2] * sv[o];

  float p = 0.f;
  p = fmaf(hf[o],       fcW[o],       p);
  p = fmaf(hf[128 + o], fcW[128 + o], p);
  p = fmaf(hf[256 + o], fcW[256 + o], p);
  p = fmaf(tf[o],       fcW[384 + o], p);
  p = fmaf(tf[128 + o], fcW[512 + o], p);
  p = fmaf(tf[256 + o], fcW[640 + o], p);
  p = fmaf(re[o],       fcW[768 + o], p);
  p = fmaf(va,          fcW[896 + o], p);
  red[o] = p;
  __syncthreads();
  if (o == 0) {
    float s = 0.f;
    for (int i = 0; i < 128; ++i) s += red[i];
    out[b] = s + fcB[0];
  }
}

extern "C" void kernel_launch(void* const* d_in, const int* in_sizes, int n_in,
                              void* d_out, int out_size, void* d_ws, size_t ws_size,
                              hipStream_t stream) {
  const float* x        = (const float*)d_in[0];
  const float* W_rel    = (const float*)d_in[1];
  const float* W_self   = (const float*)d_in[2];
  const float* rel_tb   = (const float*)d_in[3];
  const float* Zn       = (const float*)d_in[4];
  const float* proj_W   = (const float*)d_in[5];
  const float* proj_b   = (const float*)d_in[6];
  const float* fc_W     = (const float*)d_in[7];
  const float* fc_b     = (const float*)d_in[8];
  const float* rep_seq  = (const float*)d_in[9];
  const int* src      = (const int*)d_in[10];
  const int* dst      = (const int*)d_in[11];
  const int* etype    = (const int*)d_in[12];
  const int* graph_id = (const int*)d_in[13];
  const int* head_ids = (const int*)d_in[14];
  const int* tail_ids = (const int*)d_in[15];
  const int* rel_lab  = (const int*)d_in[16];
  float* out = (float*)d_out;

  // workspace carve (~106 MB), all 16B aligned
  char* w = (char*)d_ws;
  unsigned short* A   = (unsigned short*)w; w += (size_t)N_NODES * NKA * 2;            // 65.5 MB
  unsigned short* hb  = (unsigned short*)w; w += (size_t)(NL + 1) * N_NODES * H * 2;   // 32.8 MB
  unsigned short* Bt2 = (unsigned short*)w; w += (size_t)NL * H * NKK * 2;             // 0.88 MB
  int* row_ptr2 = (int*)w;  w += (size_t)(NBIN2 + 8) * 4;                              // 1.05 MB
  int* cursor   = (int*)w;  w += (size_t)NBIN2 * 4;                                    // 1.05 MB
  int* edge_off = (int*)w;  w += (size_t)NEDGE * 4;                                    // 2.05 MB
  int* bsum     = (int*)w;  w += (size_t)256 * 4;
  // zero region: cnt | gcount | gmean
  char* z = w;
  int* cnt     = (int*)w;   w += (size_t)NBIN2 * 4;                                    // 1.05 MB
  int* gcount  = (int*)w;   w += (size_t)32 * 4;
  float* gmean = (float*)w; w += (size_t)BSZ * NL * H * 4;
  size_t zbytes = (size_t)(w - z);

  hipMemsetAsync(z, 0, zbytes, stream);
  k_prep <<<7853, 256, 0, stream>>>(x, W_rel, W_self, dst, etype, graph_id, hb, Bt2, cnt, gcount);
  k_scanA<<<NBIN2 / 1024, 256, 0, stream>>>(cnt, bsum);
  k_scanC<<<NBIN2 / 1024, 256, 0, stream>>>(cnt, bsum, row_ptr2, cursor);
  k_fill <<<NEDGE / 256, 256, 0, stream>>>(src, dst, etype, cursor, edge_off);

  for (int l = 0; l < NL; ++l) {
    const unsigned short* hp = hb + (size_t)l * N_NODES * H;
    unsigned short* hn = hb + (size_t)(l + 1) * N_NODES * H;
    k_agg  <<<N_NODES, 256, 0, stream>>>(hp, row_ptr2, edge_off, A);
    k_gemmA<<<N_NODES / 64, 256, 0, stream>>>(A, Bt2 + (size_t)l * H * NKK, hp, hn, gmean, l);
  }
  k_final<<<BSZ, H, 0, stream>>>(hb, gmean, gcount, rel_tb, Zn, proj_W, proj_b, fc_W, fc_b,
                                 rep_seq, head_ids, tail_ids, rel_lab, out);
  (void)in_sizes; (void)n_in; (void)out_size; (void)ws_size;
}

// Round 9
// 329.636 us; speedup vs baseline: 1.0508x; 1.0508x over previous
//
#include <hip/hip_runtime.h>

#define N_NODES 32000
#define NPG     1000
#define BSZ     32
#define NEDGE   512000
#define H       128
#define NL      3
#define NR      8
#define NKK     1152    // B K dim: 8*128 rel chunks + 128 self chunk
#define NKA     1024    // A K dim (rel chunks only; self read from h directly)
#define NBIN2   262144  // 32768 dst bins x 8 rel sub-bins (pow2-padded; bins >= 256000 empty)

typedef __attribute__((ext_vector_type(8))) short short8;
typedef __attribute__((ext_vector_type(4))) float float4v;

__device__ __forceinline__ float bf2f(unsigned short u) {
  union { unsigned int i; float f; } v;
  v.i = ((unsigned int)u) << 16;
  return v.f;
}
__device__ __forceinline__ unsigned short f2bf(float f) {
  union { float f; unsigned int i; } v;
  v.f = f;
  unsigned int x = v.i;
  return (unsigned short)((x + 0x7FFFu + ((x >> 16) & 1u)) >> 16);  // RNE
}

// direct global->LDS DMA, 16B per lane (dest = wave-uniform base + lane*16)
__device__ __forceinline__ void gl_lds16(const void* g, void* l) {
  __builtin_amdgcn_global_load_lds((__attribute__((address_space(1))) void*)g,
                                   (__attribute__((address_space(3))) void*)l,
                                   16, 0, 0);
}

// ---------------- fused prep: cvtX | per-(dst,rel) count | graph hist ----------
__global__ __launch_bounds__(256) void k_prep(
    const float* __restrict__ x, const int* __restrict__ dst,
    const int* __restrict__ etype, const int* __restrict__ graph_id,
    unsigned short* __restrict__ hb, int* __restrict__ cnt, int* __restrict__ gcount)
{
  const int b = blockIdx.x, t = threadIdx.x;
  if (b < 4000) {                       // x fp32 -> h0 bf16
    const size_t i = ((size_t)b * 256 + t) * 4;
    float4 v = *(const float4*)(x + i);
    ushort4 u = { f2bf(v.x), f2bf(v.y), f2bf(v.z), f2bf(v.w) };
    *(ushort4*)(hb + i) = u;
  } else if (b < 6000) {                // per-(dst,rel) edge counts
    const int e = (b - 4000) * 256 + t;
    atomicAdd(&cnt[dst[e] * 8 + etype[e]], 1);
  } else {                              // graph histogram (125 blocks)
    __shared__ int hist[BSZ];
    if (t < BSZ) hist[t] = 0;
    __syncthreads();
    const int n = (b - 6000) * 256 + t;
    if (n < N_NODES) atomicAdd(&hist[graph_id[n]], 1);
    __syncthreads();
    if (t < BSZ) { int v = hist[t]; if (v) atomicAdd(&gcount[t], v); }
  }
}

// ---------------- weight transpose via LDS tiles: Bt2[l][o][rr*128+i] ----------------
// One block per (l, rr): 128x128 fp32 tile, coalesced reads, LDS pitch 137 (2-way
// conflicts only), coalesced ushort4 writes. rr<8: W_rel[l][rr]; rr==8: W_self[l].
__global__ __launch_bounds__(256) void k_wt(
    const float* __restrict__ W_rel, const float* __restrict__ W_self,
    unsigned short* __restrict__ Bt)
{
  __shared__ unsigned short T[128 * 137];
  const int t = threadIdx.x;
  const int l = blockIdx.x / 9, rr = blockIdx.x % 9;
  const float* src = (rr < 8) ? W_rel + ((size_t)l * NR + rr) * H * H
                              : W_self + (size_t)l * H * H;
  #pragma unroll
  for (int ph = 0; ph < 16; ++ph) {
    const int i  = ph * 8 + (t >> 5);
    const int o4 = (t & 31) * 4;
    float4 v = *(const float4*)(src + (size_t)i * H + o4);
    T[(o4 + 0) * 137 + i] = f2bf(v.x);
    T[(o4 + 1) * 137 + i] = f2bf(v.y);
    T[(o4 + 2) * 137 + i] = f2bf(v.z);
    T[(o4 + 3) * 137 + i] = f2bf(v.w);
  }
  __syncthreads();
  #pragma unroll
  for (int ph = 0; ph < 16; ++ph) {
    const int o  = ph * 8 + (t >> 5);
    const int i4 = (t & 31) * 4;
    ushort4 u = { T[o * 137 + i4], T[o * 137 + i4 + 1],
                  T[o * 137 + i4 + 2], T[o * 137 + i4 + 3] };
    *(ushort4*)(Bt + (size_t)l * (H * NKK) + (size_t)o * NKK + rr * 128 + i4) = u;
  }
}

// ---------------- 2-phase exclusive scan over NBIN2 bins ----------
__global__ __launch_bounds__(256) void k_scanA(const int* __restrict__ cnt,
                                               int* __restrict__ bsum) {
  __shared__ int red[256];
  const int t = threadIdx.x;
  int4 v = *(const int4*)(cnt + blockIdx.x * 1024 + t * 4);
  red[t] = v.x + v.y + v.z + v.w;
  __syncthreads();
  for (int off = 128; off > 0; off >>= 1) {
    if (t < off) red[t] += red[t + off];
    __syncthreads();
  }
  if (t == 0) bsum[blockIdx.x] = red[0];
}

__global__ __launch_bounds__(256) void k_scanC(const int* __restrict__ cnt,
                                               const int* __restrict__ bsum,
                                               int* __restrict__ row_ptr2,
                                               int* __restrict__ cursor) {
  __shared__ int ts[256], bsx[256];
  const int t = threadIdx.x;
  const int base = blockIdx.x * 1024 + t * 4;
  int4 v = *(const int4*)(cnt + base);
  const int s = v.x + v.y + v.z + v.w;
  ts[t]  = s;
  bsx[t] = bsum[t];
  __syncthreads();
  for (int off = 1; off < 256; off <<= 1) {   // inclusive Hillis-Steele, both arrays
    int a = (t >= off) ? ts[t - off]  : 0;
    int c = (t >= off) ? bsx[t - off] : 0;
    __syncthreads();
    ts[t] += a; bsx[t] += c;
    __syncthreads();
  }
  const int boff = (blockIdx.x == 0) ? 0 : bsx[blockIdx.x - 1];
  int ex = ts[t] - s + boff;
  int4 w = { ex, ex + v.x, ex + v.x + v.y, ex + v.x + v.y + v.z };
  *(int4*)(row_ptr2 + base) = w;
  *(int4*)(cursor + base) = w;
}

// ---------------- fill: edge_off[p] = src, grouped by (dst,rel) ----
__global__ void k_fill(const int* __restrict__ src, const int* __restrict__ dst,
                       const int* __restrict__ etype, int* __restrict__ cursor,
                       int* __restrict__ edge_off) {
  int e = blockIdx.x * blockDim.x + threadIdx.x;
  if (e < NEDGE) {
    int p = atomicAdd(&cursor[dst[e] * 8 + etype[e]], 1);
    edge_off[p] = src[e];
  }
}

// ---------------- aggregate: A[n][r*128+i] = sum_{e in bin(n,r)} h[src_e][i] ---------
// v4: half-wave per (node,rel) bin; uint4 row loads (16 lanes/row); lane-parity p
// handles edges k, k+2, ... ; parities combined by shfl_xor(16). 2 slots/parity
// in flight = 4 edges/iteration. No self chunk (GEMM reads h directly).
__global__ __launch_bounds__(256) void k_agg(
    const unsigned short* __restrict__ Hin,   // [N,128] bf16
    const int* __restrict__ row_ptr2,         // [N*8+1] bin offsets
    const int* __restrict__ edge_off,         // [E] src node ids
    unsigned short* __restrict__ A)           // [N,1024] bf16
{
  const int tid = threadIdx.x;
  const int j  = tid >> 5;          // rel bin 0..7
  const int li = tid & 31;
  const int p  = li >> 4;           // edge parity
  const int q  = li & 15;           // col chunk: cols q*8 .. q*8+7
  const int n  = blockIdx.x;
  const uint4* H4 = (const uint4*)Hin;   // one h row = 16 uint4
  const int b = row_ptr2[n * 8 + j];
  const int e = row_ptr2[n * 8 + j + 1];
  float acc[8] = {0.f, 0.f, 0.f, 0.f, 0.f, 0.f, 0.f, 0.f};
#define ACC8(u, ok) { \
    const unsigned int xx = (ok) ? (u).x : 0u, yy = (ok) ? (u).y : 0u; \
    const unsigned int zz = (ok) ? (u).z : 0u, ww = (ok) ? (u).w : 0u; \
    acc[0] += bf2f((unsigned short)(xx & 0xffff)); \
    acc[1] += bf2f((unsigned short)(xx >> 16));    \
    acc[2] += bf2f((unsigned short)(yy & 0xffff)); \
    acc[3] += bf2f((unsigned short)(yy >> 16));    \
    acc[4] += bf2f((unsigned short)(zz & 0xffff)); \
    acc[5] += bf2f((unsigned short)(zz >> 16));    \
    acc[6] += bf2f((unsigned short)(ww & 0xffff)); \
    acc[7] += bf2f((unsigned short)(ww >> 16)); }
  for (int k = b + p; k < e; k += 4) {   // this parity's edges: k, k+2
    const int k1 = k + 2;
    const bool v1 = k1 < e;
    const int o0 = edge_off[k];
    const int o1 = edge_off[v1 ? k1 : k];
    uint4 u0 = H4[(size_t)o0 * 16 + q];
    uint4 u1 = H4[(size_t)o1 * 16 + q];
    ACC8(u0, true)
    ACC8(u1, v1)
  }
#undef ACC8
  #pragma unroll
  for (int i = 0; i < 8; ++i) acc[i] += __shfl_xor(acc[i], 16);
  if (p == 0) {
    uint4 w;
    w.x = (unsigned int)f2bf(acc[0]) | ((unsigned int)f2bf(acc[1]) << 16);
    w.y = (unsigned int)f2bf(acc[2]) | ((unsigned int)f2bf(acc[3]) << 16);
    w.z = (unsigned int)f2bf(acc[4]) | ((unsigned int)f2bf(acc[5]) << 16);
    w.w = (unsigned int)f2bf(acc[6]) | ((unsigned int)f2bf(acc[7]) << 16);
    *(uint4*)(A + (size_t)n * NKA + j * H + q * 8) = w;
  }
}

// ---------------- GEMM: Hout = relu([A | h] @ Bt2^T), K = 1024 + 128 ------------------
// v5 (R7-proven): counted-vmcnt double-buffer: per K-step wait vmcnt(6) — next tile's
// 6 global_load_lds stay in flight; only the peeled last tile drains. 48KB LDS ->
// 3 blocks/CU (occupancy > pipeline depth; R8's 2-deep at 2 blocks/CU regressed).
__global__ __launch_bounds__(256, 3) void k_gemmA(
    const unsigned short* __restrict__ Ag,    // [32000][1024] bf16
    const unsigned short* __restrict__ Bg,    // [128][1152]   bf16
    const unsigned short* __restrict__ Hin,   // [32000][128]  bf16 (self operand)
    unsigned short* __restrict__ Hout,        // [32000][128]  bf16
    float* __restrict__ gmean, int layer)
{
  __shared__ __align__(16) unsigned short pool[24576];  // a0[4096] b0[8192] a1[4096] b1[8192]
  const int tid = threadIdx.x;
  const int w = tid >> 6, lane = tid & 63;
  const int l15 = lane & 15, quad = lane >> 4;
  const int m0 = blockIdx.x * 64;
  const int rbase = (w & 1) * 32;     // C row group (M): 0 or 32
  const int cbase = (w >> 1) * 64;    // C col group (N): 0 or 64

  float4v acc[2][4];
  #pragma unroll
  for (int i = 0; i < 2; ++i)
    #pragma unroll
    for (int jj = 0; jj < 4; ++jj) acc[i][jj] = (float4v){0.f, 0.f, 0.f, 0.f};

  // stage helpers: 2 + 4 = 6 gl_lds per thread per K-tile
  auto stageA = [&](unsigned short* dstL, const int kb) {
    #pragma unroll
    for (int rep = 0; rep < 2; ++rep) {
      const int g = rep * 256 + tid, row = g >> 3, c = g & 7;
      const unsigned short* srcp = (kb < NKA)
          ? Ag  + (size_t)(m0 + row) * NKA + kb + ((c ^ (row & 7)) * 8)
          : Hin + (size_t)(m0 + row) * H + (kb - NKA) + ((c ^ (row & 7)) * 8);
      gl_lds16(srcp, dstL + (size_t)g * 8);
    }
  };
  auto stageB = [&](unsigned short* dstL, const int kb) {
    #pragma unroll
    for (int rep = 0; rep < 4; ++rep) {
      const int g = rep * 256 + tid, row = g >> 3, c = g & 7;
      gl_lds16(Bg + (size_t)row * NKK + kb + ((c ^ (row & 7)) * 8), dstL + (size_t)g * 8);
    }
  };
  auto compute = [&](const unsigned short* ac, const unsigned short* bc) {
    #pragma unroll
    for (int s = 0; s < 2; ++s) {
      const int c = s * 4 + quad;    // 16B chunk index within 128B row
      short8 af[2], bfv[4];
      #pragma unroll
      for (int i = 0; i < 2; ++i) {
        const int row = rbase + i * 16 + l15;
        af[i] = *(const short8*)(ac + row * 64 + ((c ^ (row & 7)) * 8));
      }
      #pragma unroll
      for (int jj = 0; jj < 4; ++jj) {
        const int orow = cbase + jj * 16 + l15;
        bfv[jj] = *(const short8*)(bc + orow * 64 + ((c ^ (orow & 7)) * 8));
      }
      #pragma unroll
      for (int i = 0; i < 2; ++i)
        #pragma unroll
        for (int jj = 0; jj < 4; ++jj)
          acc[i][jj] = __builtin_amdgcn_mfma_f32_16x16x32_bf16(af[i], bfv[jj], acc[i][jj], 0, 0, 0);
    }
  };

  // prologue: tile 0 fully staged + drained
  stageA(pool, 0);
  stageB(pool + 4096, 0);
  asm volatile("s_waitcnt vmcnt(0)" ::: "memory");
  __builtin_amdgcn_s_barrier();
  __builtin_amdgcn_sched_barrier(0);

  #pragma unroll 2
  for (int kt = 0; kt < 17; ++kt) {
    const int cur = kt & 1;
    const unsigned short* ac = pool + (cur ? 12288 : 0);
    const unsigned short* bc = pool + (cur ? 16384 : 4096);
    const int kb = (kt + 1) * 64;
    stageA(pool + (cur ? 0 : 12288), kb);       // 6 loads for kt+1, left in flight
    stageB(pool + (cur ? 4096 : 16384), kb);
    asm volatile("s_waitcnt vmcnt(6)" ::: "memory");  // kt's 6 loads complete
    __builtin_amdgcn_s_barrier();
    __builtin_amdgcn_sched_barrier(0);          // pin ds_reads below the wait (rule #18)
    compute(ac, bc);
    __builtin_amdgcn_sched_barrier(0);
    __builtin_amdgcn_s_barrier();               // all reads of buf[cur] done before overwrite
  }
  // peeled last tile (kt = 17): drain its 6 loads
  asm volatile("s_waitcnt vmcnt(0)" ::: "memory");
  __builtin_amdgcn_s_barrier();
  __builtin_amdgcn_sched_barrier(0);
  compute(pool + 12288, pool + 16384);
  __syncthreads();   // all compute done before repack overwrites pool

  // epilogue: relu -> bf16 repack in LDS (stride 136) -> coalesced uint4 stores
  #pragma unroll
  for (int i = 0; i < 2; ++i)
    #pragma unroll
    for (int jj = 0; jj < 4; ++jj)
      #pragma unroll
      for (int r = 0; r < 4; ++r) {
        const int row = rbase + i * 16 + quad * 4 + r;
        const int col = cbase + jj * 16 + l15;
        pool[row * 136 + col] = f2bf(fmaxf(acc[i][jj][r], 0.f));
      }
  __syncthreads();
  #pragma unroll
  for (int rep = 0; rep < 4; ++rep) {
    const int g = rep * 256 + tid;  // 1024 chunks = 64 rows x 16
    const int row = g >> 4, c = g & 15;
    *(uint4*)(Hout + (size_t)(m0 + row) * H + c * 8) = *(const uint4*)(pool + row * 136 + c * 8);
  }

  // fused per-graph mean accumulation (block straddles <= 1 graph boundary)
  const int g0 = m0 / NPG;
  const int bnd = (g0 + 1) * NPG - m0;   // rows of this tile belonging to g0
  if (tid < H) {
    float s0 = 0.f, s1 = 0.f;
    #pragma unroll 8
    for (int r2 = 0; r2 < 64; ++r2) {
      float v = bf2f(pool[r2 * 136 + tid]);
      if (r2 < bnd) s0 += v; else s1 += v;
    }
    atomicAdd(&gmean[(size_t)g0 * (NL * H) + layer * H + tid], s0);
    if (bnd < 64)
      atomicAdd(&gmean[(size_t)(g0 + 1) * (NL * H) + layer * H + tid], s1);
  }
}

// ---------------- readout ----------------
__global__ __launch_bounds__(128) void k_final(
    const unsigned short* __restrict__ hb, const float* __restrict__ gmean,
    const int* __restrict__ gcount,
    const float* __restrict__ rel_tb, const float* __restrict__ Zn,
    const float* __restrict__ projW, const float* __restrict__ projB,
    const float* __restrict__ fcW, const float* __restrict__ fcB,
    const float* __restrict__ repSeq,
    const int* __restrict__ head_ids, const int* __restrict__ tail_ids,
    const int* __restrict__ rel_lab, float* __restrict__ out)
{
  const int b = blockIdx.x;
  const int o = threadIdx.x;   // 128
  __shared__ float gm[384], hf[384], tf[384];
  __shared__ float go[128], ho[128], t_o[128], re[128], rs[128], sv[128];
  __shared__ float lg[128], pr[128], red[128], att[3];

  const int hid = head_ids[b], tlid = tail_ids[b], rl = rel_lab[b];
  const float cinv = 1.f / (float)gcount[b];
  #pragma unroll
  for (int l = 0; l < NL; ++l) {
    gm[l * H + o] = gmean[(size_t)b * (NL * H) + l * H + o] * cinv;
    hf[l * H + o] = bf2f(hb[((size_t)(l + 1) * N_NODES + hid) * H + o]);
    tf[l * H + o] = bf2f(hb[((size_t)(l + 1) * N_NODES + tlid) * H + o]);
  }
  re[o] = rel_tb[rl * H + o];
  rs[o] = repSeq[b * H + o];
  __syncthreads();

  float pb = projB[o];
  float sg = pb, sh = pb, st = pb;
  for (int i = 0; i < NL * H; ++i) {
    float wv = projW[i * H + o];
    sg = fmaf(gm[i], wv, sg);
    sh = fmaf(hf[i], wv, sh);
    st = fmaf(tf[i], wv, st);
  }
  go[o] = (sg > 0.f) ? sg : 0.01f * sg;
  ho[o] = sh;
  t_o[o] = st;
  __syncthreads();

  {
    const int k = o & 63;
    const float* v = (o < 64) ? ho : t_o;
    float s = 0.f;
    for (int i = 0; i < H; ++i) s = fmaf(v[i], Zn[k * H + i], s);
    lg[o] = s;
  }
  __syncthreads();
  if (o < 2) {
    float* l0 = &lg[o * 64];
    float* p0 = &pr[o * 64];
    float mx = l0[0];
    for (int k = 1; k < 64; ++k) mx = fmaxf(mx, l0[k]);
    float sum = 0.f;
    for (int k = 0; k < 64; ++k) { float e = __expf(l0[k] - mx); p0[k] = e; sum += e; }
    float inv = 1.f / sum;
    for (int k = 0; k < 64; ++k) p0[k] *= inv;
  }
  __syncthreads();
  {
    float s1 = 0.f, s2 = 0.f;
    for (int k = 0; k < 64; ++k) {
      float z = Zn[k * H + o];
      s1 = fmaf(pr[k], z, s1);
      s2 = fmaf(pr[64 + k], z, s2);
    }
    s1 = 1.f / (1.f + __expf(-s1));
    s2 = 1.f / (1.f + __expf(-s2));
    sv[o] = s1 * s2;
  }
  __syncthreads();
  if (o == 0) {
    float d0 = 0.f, d1 = 0.f, d2 = 0.f;
    for (int i = 0; i < H; ++i) { d0 += re[i] * go[i]; d1 += re[i] * rs[i]; d2 += re[i] * sv[i]; }
    float mx = fmaxf(d0, fmaxf(d1, d2));
    float e0 = __expf(d0 - mx), e1 = __expf(d1 - mx), e2 = __expf(d2 - mx);
    float inv = 1.f / (e0 + e1 + e2);
    att[0] = e0 * inv; att[1] = e1 * inv; att[2] = e2 * inv;
  }
  __syncthreads();
  float va = att[0] * go[o] + att[1] * rs[o] + att[2] * sv[o];

  float p = 0.f;
  p = fmaf(hf[o],       fcW[o],       p);
  p = fmaf(hf[128 + o], fcW[128 + o], p);
  p = fmaf(hf[256 + o], fcW[256 + o], p);
  p = fmaf(tf[o],       fcW[384 + o], p);
  p = fmaf(tf[128 + o], fcW[512 + o], p);
  p = fmaf(tf[256 + o], fcW[640 + o], p);
  p = fmaf(re[o],       fcW[768 + o], p);
  p = fmaf(va,          fcW[896 + o], p);
  red[o] = p;
  __syncthreads();
  if (o == 0) {
    float s = 0.f;
    for (int i = 0; i < 128; ++i) s += red[i];
    out[b] = s + fcB[0];
  }
}

extern "C" void kernel_launch(void* const* d_in, const int* in_sizes, int n_in,
                              void* d_out, int out_size, void* d_ws, size_t ws_size,
                              hipStream_t stream) {
  const float* x        = (const float*)d_in[0];
  const float* W_rel    = (const float*)d_in[1];
  const float* W_self   = (const float*)d_in[2];
  const float* rel_tb   = (const float*)d_in[3];
  const float* Zn       = (const float*)d_in[4];
  const float* proj_W   = (const float*)d_in[5];
  const float* proj_b   = (const float*)d_in[6];
  const float* fc_W     = (const float*)d_in[7];
  const float* fc_b     = (const float*)d_in[8];
  const float* rep_seq  = (const float*)d_in[9];
  const int* src      = (const int*)d_in[10];
  const int* dst      = (const int*)d_in[11];
  const int* etype    = (const int*)d_in[12];
  const int* graph_id = (const int*)d_in[13];
  const int* head_ids = (const int*)d_in[14];
  const int* tail_ids = (const int*)d_in[15];
  const int* rel_lab  = (const int*)d_in[16];
  float* out = (float*)d_out;

  // workspace carve (~106 MB), all 16B aligned
  char* w = (char*)d_ws;
  unsigned short* A   = (unsigned short*)w; w += (size_t)N_NODES * NKA * 2;            // 65.5 MB
  unsigned short* hb  = (unsigned short*)w; w += (size_t)(NL + 1) * N_NODES * H * 2;   // 32.8 MB
  unsigned short* Bt2 = (unsigned short*)w; w += (size_t)NL * H * NKK * 2;             // 0.88 MB
  int* row_ptr2 = (int*)w;  w += (size_t)(NBIN2 + 8) * 4;                              // 1.05 MB
  int* cursor   = (int*)w;  w += (size_t)NBIN2 * 4;                                    // 1.05 MB
  int* edge_off = (int*)w;  w += (size_t)NEDGE * 4;                                    // 2.05 MB
  int* bsum     = (int*)w;  w += (size_t)256 * 4;
  // zero region: cnt | gcount | gmean
  char* z = w;
  int* cnt     = (int*)w;   w += (size_t)NBIN2 * 4;                                    // 1.05 MB
  int* gcount  = (int*)w;   w += (size_t)32 * 4;
  float* gmean = (float*)w; w += (size_t)BSZ * NL * H * 4;
  size_t zbytes = (size_t)(w - z);

  hipMemsetAsync(z, 0, zbytes, stream);
  k_prep <<<6125, 256, 0, stream>>>(x, dst, etype, graph_id, hb, cnt, gcount);
  k_wt   <<<27, 256, 0, stream>>>(W_rel, W_self, Bt2);
  k_scanA<<<NBIN2 / 1024, 256, 0, stream>>>(cnt, bsum);
  k_scanC<<<NBIN2 / 1024, 256, 0, stream>>>(cnt, bsum, row_ptr2, cursor);
  k_fill <<<NEDGE / 256, 256, 0, stream>>>(src, dst, etype, cursor, edge_off);

  for (int l = 0; l < NL; ++l) {
    const unsigned short* hp = hb + (size_t)l * N_NODES * H;
    unsigned short* hn = hb + (size_t)(l + 1) * N_NODES * H;
    k_agg  <<<N_NODES, 256, 0, stream>>>(hp, row_ptr2, edge_off, A);
    k_gemmA<<<N_NODES / 64, 256, 0, stream>>>(A, Bt2 + (size_t)l * H * NKK, hp, hn, gmean, l);
  }
  k_final<<<BSZ, H, 0, stream>>>(hb, gmean, gcount, rel_tb, Zn, proj_W, proj_b, fc_W, fc_b,
                                 rep_seq, head_ids, tail_ids, rel_lab, out);
  (void)in_sizes; (void)n_in; (void)out_size; (void)ws_size;
}